// Round 9
// baseline (624.942 us; speedup 1.0000x reference)
//
#include <hip/hip_runtime.h>
#include <hip/hip_fp16.h>

// ---------------- problem constants ----------------
#define NNODES 20000
#define NEDGES 320000
#define NELEM  10
#define NC     (NNODES * 64)   // 1,280,000

// ---------------- phase-overlaid ws layout (float offsets) ----------------
// All aggregation buffers are fp16 now (half the bytes of their slots).
#define OFF_SUP1 ((size_t)0)
#define OFF_AGS1 ((size_t)1 * NC)
#define OFF_AGV1 ((size_t)2 * NC)
#define OFF_AGS2 ((size_t)0)
#define OFF_AGV2 ((size_t)2 * NC)
#define OFF_SUP2 ((size_t)8 * NC)
#define OFF_VUP2 ((size_t)9 * NC)
#define OFF_SKS2 ((size_t)12 * NC)
#define OFF_SKV2 ((size_t)13 * NC)
#define OFF_INT  ((size_t)16 * NC)
// sUp1/sUp2/vUp2 fp16. agS1 [20000][64]h, agV1 [20000][192]h,
// agS2 [20000][128]h, agV2 [20000][384]h (=[3][128] per node).
// bf16 split W3 (ushort units) after the 360000 ints:
//   w3a_hi [128][64] @0, w3a_lo @8192, w3b_hi [256][64] @16384, w3b_lo @32768

// edge-kernel smem overlay (38656 B -> 4 blocks/CU):
//   [0,768) ysh | [768,1024) ssh | [1024,1280) rsh
//   [1280,17920) h1sh f32[64][65]   (tr 4x[16][64] overlays after A2)
//   [17920,36352) h2buf u16[2][64][72] | [36352,38656) fsh f32[64][9]
#define SMEM_BYTES 38656

// XCD-aware block swizzle: grid 5000 = 8*625, bijective contiguous-chunk map.
__device__ __forceinline__ int xcd_swz(int bid) {
    return (bid & 7) * 625 + (bid >> 3);
}

typedef __attribute__((ext_vector_type(8))) short bf16x8;
typedef __attribute__((ext_vector_type(4))) float f32x4;

__device__ __forceinline__ float silu(float x) { return x / (1.0f + __expf(-x)); }
__device__ __forceinline__ int rfl(int v) { return __builtin_amdgcn_readfirstlane(v); }
__device__ __forceinline__ int rl_i(int v, int l) { return __builtin_amdgcn_readlane(v, l); }
__device__ __forceinline__ float rl_f(float v, int l) {
    return __int_as_float(__builtin_amdgcn_readlane(__float_as_int(v), l));
}
// split two f32 into packed bf16 hi-pair (x) and lo-pair (y), round-to-nearest
__device__ __forceinline__ uint2 split2(float x0, float x1) {
    unsigned int b0 = __float_as_uint(x0), b1 = __float_as_uint(x1);
    unsigned int h0 = (b0 + 0x7FFF + ((b0 >> 16) & 1)) & 0xFFFF0000u;
    unsigned int h1 = (b1 + 0x7FFF + ((b1 >> 16) & 1)) & 0xFFFF0000u;
    unsigned int l0 = __float_as_uint(x0 - __uint_as_float(h0));
    unsigned int l1 = __float_as_uint(x1 - __uint_as_float(h1));
    unsigned int hi = (h0 >> 16) | (h1 & 0xFFFF0000u);
    unsigned int lo = ((l0 + 0x7FFF + ((l0 >> 16) & 1)) >> 16)
                    | ((l1 + 0x7FFF + ((l1 >> 16) & 1)) & 0xFFFF0000u);
    return make_uint2(hi, lo);
}

// fp16 packed-atomic flush: lane l holds v for channel (base+l); even lanes
// issue one half2 hardware atomic covering channels (l, l+1).
__device__ __forceinline__ void flush2(__half* base, int lane, float v) {
    float p = __shfl_xor(v, 1);
    if (!(lane & 1)) {
        __half2 h2 = __halves2half2(__float2half_rn(v), __float2half_rn(p));
        unsafeAtomicAdd((__half2*)(base + lane), h2);
    }
}

// ---------------- weight split: W3 -> transposed bf16 hi/lo ----------------
__global__ __launch_bounds__(256) void k_wsplit(
    const float* __restrict__ W3a, const float* __restrict__ W3b,
    unsigned short* __restrict__ out)
{
    int t = blockIdx.x * 256 + threadIdx.x;   // 24576 total
    float x; unsigned short *ph, *pl; int idx;
    if (t < 8192) {
        int n = t >> 6, k = t & 63;
        x = W3a[k * 128 + n]; ph = out; pl = out + 8192; idx = n * 64 + k;
    } else {
        int u = t - 8192; int n = u >> 6, k = u & 63;
        x = W3b[k * 256 + n]; ph = out + 16384; pl = out + 32768; idx = n * 64 + k;
    }
    unsigned int b = __float_as_uint(x);
    unsigned int h = (b + 0x7FFF + ((b >> 16) & 1)) & 0xFFFF0000u;
    unsigned int r = __float_as_uint(x - __uint_as_float(h));
    ph[idx] = (unsigned short)(h >> 16);
    pl[idx] = (unsigned short)((r + 0x7FFF + ((r >> 16) & 1)) >> 16);
}

// ---------------- sort by rcv ----------------
__global__ __launch_bounds__(256) void k_hist(const int* __restrict__ eidx,
                                              int* __restrict__ hist)
{
    int e = blockIdx.x * 256 + threadIdx.x;
    atomicAdd(&hist[eidx[NEDGES + e]], 1);
}

__global__ __launch_bounds__(1024) void k_scan(const int* __restrict__ hist,
                                               int* __restrict__ cursor)
{
    __shared__ int wsum[16];
    __shared__ int gbase;
    int tid = threadIdx.x;
    int lane = tid & 63, wvid = tid >> 6;
    if (tid == 0) gbase = 0;
    __syncthreads();
    for (int seg = 0; seg < 20; ++seg) {
        int i = seg * 1024 + tid;
        int v = (i < NNODES) ? hist[i] : 0;
        int s = v;
        #pragma unroll
        for (int d = 1; d < 64; d <<= 1) {
            int t = __shfl_up(s, d, 64);
            if (lane >= d) s += t;
        }
        if (lane == 63) wsum[wvid] = s;
        __syncthreads();
        if (wvid == 0) {
            int w = (lane < 16) ? wsum[lane] : 0;
            #pragma unroll
            for (int d = 1; d < 16; d <<= 1) {
                int t = __shfl_up(w, d, 64);
                if (lane >= d) w += t;
            }
            if (lane < 16) wsum[lane] = w;
        }
        __syncthreads();
        int wbase = (wvid == 0) ? 0 : wsum[wvid - 1];
        if (i < NNODES) cursor[i] = gbase + wbase + s - v;
        int segtot = wsum[15];
        __syncthreads();
        if (tid == 0) gbase += segtot;
    }
}

__global__ __launch_bounds__(256) void k_scatter(const int* __restrict__ eidx,
                                                 int* __restrict__ cursor,
                                                 int* __restrict__ sorted)
{
    int e = blockIdx.x * 256 + threadIdx.x;
    int pos = atomicAdd(&cursor[eidx[NEDGES + e]], 1);
    sorted[pos] = e;
}

// ---------------- node pre ----------------
__global__ __launch_bounds__(256) void k_node_pre(
    const float* __restrict__ attrs, const float* __restrict__ Wemb,
    const float* __restrict__ U1s, __half* __restrict__ sUp1)
{
    int lane = threadIdx.x & 63, wv = threadIdx.x >> 6;
    int n = blockIdx.x * 4 + wv;
    __shared__ __align__(16) float s0sh[4][64];
    float s0 = 0.f;
    #pragma unroll
    for (int v = 0; v < NELEM; ++v) s0 += attrs[n * NELEM + v] * Wemb[v * 64 + lane];
    s0sh[wv][lane] = s0;
    __syncthreads();
    float a = 0.f;
    #pragma unroll 8
    for (int k = 0; k < 64; ++k) a += s0sh[wv][k] * U1s[k * 64 + lane];
    sUp1[n * 64 + lane] = __float2half_rn(a);
}

// ---------------- edge block 1: chunked, 4/CU, fp16 atomics ----------------
__global__ __launch_bounds__(256, 4) void k_edge1(
    const float* __restrict__ pos, const int* __restrict__ eidx,
    const float* __restrict__ shf, const int* __restrict__ sorted,
    const float* __restrict__ W1, const float* __restrict__ W2,
    const unsigned short* __restrict__ w3h, const unsigned short* __restrict__ w3l,
    const __half* __restrict__ sUp1,
    __half* __restrict__ agS1, __half* __restrict__ agV1)
{
    __shared__ __align__(16) char smem[SMEM_BYTES];
    float (*ysh)[3]   = (float (*)[3])(smem);
    int*  ssh         = (int*)(smem + 768);
    int*  rsh         = (int*)(smem + 1024);
    float (*h1sh)[65] = (float (*)[65])(smem + 1280);
    unsigned short (*h2buf)[64][72] = (unsigned short (*)[64][72])(smem + 17920);
    float (*fsh)[9]   = (float (*)[9])(smem + 36352);

    const int tid = threadIdx.x;
    const int lane = tid & 63;
    const int w = rfl(tid >> 6);
    const int e0 = xcd_swz(blockIdx.x) * 64;

    // ---- stage: 4 threads per edge ----
    {
        int e = tid >> 2, sub = tid & 3;
        int sid = sorted[e0 + e];
        int snd = eidx[sid], rcv = eidx[NEDGES + sid];
        float dx = pos[snd * 3 + 0] - pos[rcv * 3 + 0] + shf[(size_t)sid * 3 + 0];
        float dy = pos[snd * 3 + 1] - pos[rcv * 3 + 1] + shf[(size_t)sid * 3 + 1];
        float dz = pos[snd * 3 + 2] - pos[rcv * 3 + 2] + shf[(size_t)sid * 3 + 2];
        float len = sqrtf(dx * dx + dy * dy + dz * dz + 1e-12f);
        float inv = 1.0f / len;
        float u = len * 0.2f;
        float u2 = u * u, u4 = u2 * u2, u5 = u4 * u, u6 = u5 * u, u7 = u6 * u;
        float cut = (u < 1.0f) ? (1.0f - 21.0f * u5 + 35.0f * u6 - 15.0f * u7) : 0.0f;
        float s = 0.632455532033676f * inv * cut;
        #pragma unroll
        for (int kk = 0; kk < 2; ++kk) {
            int k = sub * 2 + kk;
            fsh[e][k] = s * sinf((float)(k + 1) * 0.628318530717959f * len);
        }
        if (sub == 0) {
            ssh[e] = snd; rsh[e] = rcv;
            ysh[e][0] = 1.73205080756888f * dx * inv;
            ysh[e][1] = 1.73205080756888f * dy * inv;
            ysh[e][2] = 1.73205080756888f * dz * inv;
        }
    }
    __syncthreads();

    const int rAll = rsh[lane];
    const int sAll = ssh[lane];
    const float y0A = ysh[lane][0], y1A = ysh[lane][1], y2A = ysh[lane][2];

    // ---- A1: 8->64 ----
    {
        float f[8];
        #pragma unroll
        for (int k = 0; k < 8; ++k) f[k] = fsh[lane][k];
        const float* __restrict__ w1b = W1 + w * 16;
        #pragma unroll
        for (int j = 0; j < 16; ++j) {
            float a = 0.f;
            #pragma unroll
            for (int k = 0; k < 8; ++k) a = fmaf(f[k], w1b[k * 64 + j], a);
            h1sh[lane][w * 16 + j] = silu(a);
        }
    }
    __syncthreads();

    // ---- A2: 64->64, split-bf16 epilogue ----
    {
        const float2* __restrict__ w2b = (const float2*)W2 + w * 8;
        float2 acc[8];
        #pragma unroll
        for (int j = 0; j < 8; ++j) acc[j] = make_float2(0.f, 0.f);
        for (int k = 0; k < 64; ++k) {
            float h = h1sh[lane][k];
            const float2* __restrict__ wk = w2b + k * 32;
            #pragma unroll
            for (int j = 0; j < 8; ++j) {
                float2 wv = wk[j];
                acc[j].x = fmaf(h, wv.x, acc[j].x);
                acc[j].y = fmaf(h, wv.y, acc[j].y);
            }
        }
        #pragma unroll
        for (int j = 0; j < 8; ++j) {
            uint2 p = split2(silu(acc[j].x), silu(acc[j].y));
            *(unsigned int*)&h2buf[0][lane][w * 16 + 2 * j] = p.x;
            *(unsigned int*)&h2buf[1][lane][w * 16 + 2 * j] = p.y;
        }
    }
    __syncthreads();   // h1sh dead; tr overlays it (wave-local from here)

    // ---- B: wave w owns edges [w*16, w*16+16), 2 chunks of 64 channels ----
    const int q = lane >> 4, nl = lane & 15;
    float* trw = (float*)(smem + 1280) + w * 1024;   // [16][64]

    const unsigned short* ar = &h2buf[0][w * 16 + nl][0];
    const unsigned short* al = &h2buf[1][w * 16 + nl][0];
    bf16x8 ah0 = *(const bf16x8*)(ar + q * 8);
    bf16x8 ah1 = *(const bf16x8*)(ar + 32 + q * 8);
    bf16x8 al0 = *(const bf16x8*)(al + q * 8);
    bf16x8 al1 = *(const bf16x8*)(al + 32 + q * 8);

    float sreg[16];
    #pragma unroll
    for (int i = 0; i < 16; ++i)
        sreg[i] = __half2float(sUp1[rl_i(sAll, w * 16 + i) * 64 + lane]);

    // ===== chunk 0: channels 0..63 (mA -> agS1) =====
    #pragma unroll
    for (int nt = 0; nt < 4; ++nt) {
        int c = nt * 16 + nl;
        const unsigned short* wh = w3h + c * 64 + q * 8;
        const unsigned short* wl = w3l + c * 64 + q * 8;
        bf16x8 bh0 = *(const bf16x8*)wh;
        bf16x8 bh1 = *(const bf16x8*)(wh + 32);
        bf16x8 bl0 = *(const bf16x8*)wl;
        bf16x8 bl1 = *(const bf16x8*)(wl + 32);
        f32x4 a = {0.f, 0.f, 0.f, 0.f};
        a = __builtin_amdgcn_mfma_f32_16x16x32_bf16(ah0, bh0, a, 0, 0, 0);
        a = __builtin_amdgcn_mfma_f32_16x16x32_bf16(ah1, bh1, a, 0, 0, 0);
        a = __builtin_amdgcn_mfma_f32_16x16x32_bf16(ah0, bl0, a, 0, 0, 0);
        a = __builtin_amdgcn_mfma_f32_16x16x32_bf16(ah1, bl1, a, 0, 0, 0);
        a = __builtin_amdgcn_mfma_f32_16x16x32_bf16(al0, bh0, a, 0, 0, 0);
        a = __builtin_amdgcn_mfma_f32_16x16x32_bf16(al1, bh1, a, 0, 0, 0);
        #pragma unroll
        for (int r = 0; r < 4; ++r) {
            int li = q * 4 + r;
            trw[li * 64 + ((c + 4 * li) & 63)] = a[r];
        }
    }
    {
        float accS = 0.f;
        int cur = rl_i(rAll, w * 16);
        #pragma unroll
        for (int i = 0; i < 16; ++i) {
            int e = w * 16 + i;
            int rcv = rl_i(rAll, e);
            if (rcv != cur) {
                flush2(agS1 + cur * 64, lane, accS);
                accS = 0.f; cur = rcv;
            }
            accS += trw[i * 64 + ((lane + 4 * i) & 63)] * sreg[i];
        }
        flush2(agS1 + cur * 64, lane, accS);
    }

    // ===== chunk 1: channels 64..127 (mB -> agV1) =====
    #pragma unroll
    for (int nt = 0; nt < 4; ++nt) {
        int c = nt * 16 + nl;
        int ng = 64 + c;
        const unsigned short* wh = w3h + ng * 64 + q * 8;
        const unsigned short* wl = w3l + ng * 64 + q * 8;
        bf16x8 bh0 = *(const bf16x8*)wh;
        bf16x8 bh1 = *(const bf16x8*)(wh + 32);
        bf16x8 bl0 = *(const bf16x8*)wl;
        bf16x8 bl1 = *(const bf16x8*)(wl + 32);
        f32x4 a = {0.f, 0.f, 0.f, 0.f};
        a = __builtin_amdgcn_mfma_f32_16x16x32_bf16(ah0, bh0, a, 0, 0, 0);
        a = __builtin_amdgcn_mfma_f32_16x16x32_bf16(ah1, bh1, a, 0, 0, 0);
        a = __builtin_amdgcn_mfma_f32_16x16x32_bf16(ah0, bl0, a, 0, 0, 0);
        a = __builtin_amdgcn_mfma_f32_16x16x32_bf16(ah1, bl1, a, 0, 0, 0);
        a = __builtin_amdgcn_mfma_f32_16x16x32_bf16(al0, bh0, a, 0, 0, 0);
        a = __builtin_amdgcn_mfma_f32_16x16x32_bf16(al1, bh1, a, 0, 0, 0);
        #pragma unroll
        for (int r = 0; r < 4; ++r) {
            int li = q * 4 + r;
            trw[li * 64 + ((c + 4 * li) & 63)] = a[r];
        }
    }
    {
        float b0 = 0.f, b1 = 0.f, b2 = 0.f;
        int cur = rl_i(rAll, w * 16);
        #pragma unroll
        for (int i = 0; i < 16; ++i) {
            int e = w * 16 + i;
            int rcv = rl_i(rAll, e);
            if (rcv != cur) {
                flush2(agV1 + cur * 192,       lane, b0);
                flush2(agV1 + cur * 192 +  64, lane, b1);
                flush2(agV1 + cur * 192 + 128, lane, b2);
                b0 = b1 = b2 = 0.f; cur = rcv;
            }
            float msg = trw[i * 64 + ((lane + 4 * i) & 63)] * sreg[i];
            b0 += msg * rl_f(y0A, e);
            b1 += msg * rl_f(y1A, e);
            b2 += msg * rl_f(y2A, e);
        }
        flush2(agV1 + cur * 192,       lane, b0);
        flush2(agV1 + cur * 192 +  64, lane, b1);
        flush2(agV1 + cur * 192 + 128, lane, b2);
    }
}

// ---------------- node mid ----------------
__global__ __launch_bounds__(256) void k_node_mid(
    const float* __restrict__ attrs, const float* __restrict__ Wemb,
    const float* __restrict__ K1s, const float* __restrict__ L1s,
    const float* __restrict__ L1v,
    const float* __restrict__ U2s, const float* __restrict__ U2v,
    const float* __restrict__ K2s, const float* __restrict__ K2v,
    const __half* __restrict__ agS1, const __half* __restrict__ agV1,
    __half* __restrict__ sUp2, __half* __restrict__ vUp2,
    float* __restrict__ skS2, float* __restrict__ skV2)
{
    int lane = threadIdx.x & 63, wv = threadIdx.x >> 6;
    int n = blockIdx.x * 4 + wv;
    __shared__ float aSsh[4][64];
    __shared__ float aVsh[4][3][64];
    __shared__ float s0sh[4][64];
    __shared__ float s1sh[4][64];
    __shared__ float v1sh[4][3][64];

    int sp = 0;
    #pragma unroll
    for (int v = 0; v < NELEM; ++v) if (attrs[n * NELEM + v] > 0.5f) sp = v;
    aSsh[wv][lane] = __half2float(agS1[n * 64 + lane]);
    #pragma unroll
    for (int i = 0; i < 3; ++i)
        aVsh[wv][i][lane] = __half2float(agV1[n * 192 + i * 64 + lane]);
    s0sh[wv][lane] = Wemb[sp * 64 + lane];
    __syncthreads();

    float s1 = 0.f;
    #pragma unroll 8
    for (int k = 0; k < 64; ++k) s1 += aSsh[wv][k] * L1s[k * 64 + lane];
    #pragma unroll 8
    for (int k = 0; k < 64; ++k) s1 += s0sh[wv][k] * K1s[(k * NELEM + sp) * 64 + lane];
    float v1[3] = {0.f, 0.f, 0.f};
    #pragma unroll 8
    for (int k = 0; k < 64; ++k) {
        float w = L1v[k * 64 + lane];
        v1[0] += aVsh[wv][0][k] * w;
        v1[1] += aVsh[wv][1][k] * w;
        v1[2] += aVsh[wv][2][k] * w;
    }
    s1sh[wv][lane] = s1;
    #pragma unroll
    for (int i = 0; i < 3; ++i) v1sh[wv][i][lane] = v1[i];
    __syncthreads();

    float su = 0.f, ks = 0.f;
    float vu[3] = {0.f, 0.f, 0.f}, kv[3] = {0.f, 0.f, 0.f};
    #pragma unroll 8
    for (int k = 0; k < 64; ++k) su += s1sh[wv][k] * U2s[k * 64 + lane];
    #pragma unroll 8
    for (int k = 0; k < 64; ++k) ks += s1sh[wv][k] * K2s[(k * NELEM + sp) * 64 + lane];
    #pragma unroll 8
    for (int k = 0; k < 64; ++k) {
        float w = U2v[k * 64 + lane];
        vu[0] += v1sh[wv][0][k] * w;
        vu[1] += v1sh[wv][1][k] * w;
        vu[2] += v1sh[wv][2][k] * w;
    }
    #pragma unroll 8
    for (int k = 0; k < 64; ++k) {
        float w = K2v[(k * NELEM + sp) * 64 + lane];
        kv[0] += v1sh[wv][0][k] * w;
        kv[1] += v1sh[wv][1][k] * w;
        kv[2] += v1sh[wv][2][k] * w;
    }
    sUp2[n * 64 + lane] = __float2half_rn(su);
    skS2[n * 64 + lane] = ks;
    #pragma unroll
    for (int i = 0; i < 3; ++i) {
        vUp2[n * 192 + i * 64 + lane] = __float2half_rn(vu[i]);
        skV2[n * 192 + i * 64 + lane] = kv[i];
    }
}

// ---------------- edge block 2: chunked 4x64-ch, 4/CU, fp16 atomics --------
__global__ __launch_bounds__(256, 4) void k_edge2(
    const float* __restrict__ pos, const int* __restrict__ eidx,
    const float* __restrict__ shf, const int* __restrict__ sorted,
    const float* __restrict__ W1, const float* __restrict__ W2,
    const unsigned short* __restrict__ w3h, const unsigned short* __restrict__ w3l,
    const __half* __restrict__ sUp2, const __half* __restrict__ vUp2,
    __half* __restrict__ agS2, __half* __restrict__ agV2)
{
    __shared__ __align__(16) char smem[SMEM_BYTES];
    float (*ysh)[3]   = (float (*)[3])(smem);
    int*  ssh         = (int*)(smem + 768);
    int*  rsh         = (int*)(smem + 1024);
    float (*h1sh)[65] = (float (*)[65])(smem + 1280);
    unsigned short (*h2buf)[64][72] = (unsigned short (*)[64][72])(smem + 17920);
    float (*fsh)[9]   = (float (*)[9])(smem + 36352);

    const int tid = threadIdx.x;
    const int lane = tid & 63;
    const int w = rfl(tid >> 6);
    const int e0 = xcd_swz(blockIdx.x) * 64;

    // ---- stage: 4 threads per edge ----
    {
        int e = tid >> 2, sub = tid & 3;
        int sid = sorted[e0 + e];
        int snd = eidx[sid], rcv = eidx[NEDGES + sid];
        float dx = pos[snd * 3 + 0] - pos[rcv * 3 + 0] + shf[(size_t)sid * 3 + 0];
        float dy = pos[snd * 3 + 1] - pos[rcv * 3 + 1] + shf[(size_t)sid * 3 + 1];
        float dz = pos[snd * 3 + 2] - pos[rcv * 3 + 2] + shf[(size_t)sid * 3 + 2];
        float len = sqrtf(dx * dx + dy * dy + dz * dz + 1e-12f);
        float inv = 1.0f / len;
        float u = len * 0.2f;
        float u2 = u * u, u4 = u2 * u2, u5 = u4 * u, u6 = u5 * u, u7 = u6 * u;
        float cut = (u < 1.0f) ? (1.0f - 21.0f * u5 + 35.0f * u6 - 15.0f * u7) : 0.0f;
        float s = 0.632455532033676f * inv * cut;
        #pragma unroll
        for (int kk = 0; kk < 2; ++kk) {
            int k = sub * 2 + kk;
            fsh[e][k] = s * sinf((float)(k + 1) * 0.628318530717959f * len);
        }
        if (sub == 0) {
            ssh[e] = snd; rsh[e] = rcv;
            ysh[e][0] = 1.73205080756888f * dx * inv;
            ysh[e][1] = 1.73205080756888f * dy * inv;
            ysh[e][2] = 1.73205080756888f * dz * inv;
        }
    }
    __syncthreads();

    const int rAll = rsh[lane];
    const int sAll = ssh[lane];
    const float y0A = ysh[lane][0], y1A = ysh[lane][1], y2A = ysh[lane][2];

    // ---- A1 ----
    {
        float f[8];
        #pragma unroll
        for (int k = 0; k < 8; ++k) f[k] = fsh[lane][k];
        const float* __restrict__ w1b = W1 + w * 16;
        #pragma unroll
        for (int j = 0; j < 16; ++j) {
            float a = 0.f;
            #pragma unroll
            for (int k = 0; k < 8; ++k) a = fmaf(f[k], w1b[k * 64 + j], a);
            h1sh[lane][w * 16 + j] = silu(a);
        }
    }
    __syncthreads();

    // ---- A2 with split-bf16 epilogue ----
    {
        const float2* __restrict__ w2b = (const float2*)W2 + w * 8;
        float2 acc[8];
        #pragma unroll
        for (int j = 0; j < 8; ++j) acc[j] = make_float2(0.f, 0.f);
        for (int k = 0; k < 64; ++k) {
            float h = h1sh[lane][k];
            const float2* __restrict__ wk = w2b + k * 32;
            #pragma unroll
            for (int j = 0; j < 8; ++j) {
                float2 wv = wk[j];
                acc[j].x = fmaf(h, wv.x, acc[j].x);
                acc[j].y = fmaf(h, wv.y, acc[j].y);
            }
        }
        #pragma unroll
        for (int j = 0; j < 8; ++j) {
            uint2 p = split2(silu(acc[j].x), silu(acc[j].y));
            *(unsigned int*)&h2buf[0][lane][w * 16 + 2 * j] = p.x;
            *(unsigned int*)&h2buf[1][lane][w * 16 + 2 * j] = p.y;
        }
    }
    __syncthreads();   // last block-wide barrier; everything below is wave-local

    // ---- B: wave w owns edges [w*16, w*16+16) ----
    const int q = lane >> 4, nl = lane & 15;
    float* trw = (float*)(smem + 1280) + w * 1024;   // [16][64]

    const unsigned short* ar = &h2buf[0][w * 16 + nl][0];
    const unsigned short* al = &h2buf[1][w * 16 + nl][0];
    bf16x8 ah0 = *(const bf16x8*)(ar + q * 8);
    bf16x8 ah1 = *(const bf16x8*)(ar + 32 + q * 8);
    bf16x8 al0 = *(const bf16x8*)(al + q * 8);
    bf16x8 al1 = *(const bf16x8*)(al + 32 + q * 8);

    float sreg[16];
    #pragma unroll
    for (int i = 0; i < 16; ++i)
        sreg[i] = __half2float(sUp2[rl_i(sAll, w * 16 + i) * 64 + lane]);

    // ===== chunk A: channels 0..63 (mA -> agS2 lo) =====
    #pragma unroll
    for (int nt = 0; nt < 4; ++nt) {
        int c = nt * 16 + nl;
        const unsigned short* wh = w3h + c * 64 + q * 8;
        const unsigned short* wl = w3l + c * 64 + q * 8;
        bf16x8 bh0 = *(const bf16x8*)wh;
        bf16x8 bh1 = *(const bf16x8*)(wh + 32);
        bf16x8 bl0 = *(const bf16x8*)wl;
        bf16x8 bl1 = *(const bf16x8*)(wl + 32);
        f32x4 a = {0.f, 0.f, 0.f, 0.f};
        a = __builtin_amdgcn_mfma_f32_16x16x32_bf16(ah0, bh0, a, 0, 0, 0);
        a = __builtin_amdgcn_mfma_f32_16x16x32_bf16(ah1, bh1, a, 0, 0, 0);
        a = __builtin_amdgcn_mfma_f32_16x16x32_bf16(ah0, bl0, a, 0, 0, 0);
        a = __builtin_amdgcn_mfma_f32_16x16x32_bf16(ah1, bl1, a, 0, 0, 0);
        a = __builtin_amdgcn_mfma_f32_16x16x32_bf16(al0, bh0, a, 0, 0, 0);
        a = __builtin_amdgcn_mfma_f32_16x16x32_bf16(al1, bh1, a, 0, 0, 0);
        #pragma unroll
        for (int r = 0; r < 4; ++r) {
            int li = q * 4 + r;
            trw[li * 64 + ((c + 4 * li) & 63)] = a[r];
        }
    }
    {
        float accS = 0.f;
        int cur = rl_i(rAll, w * 16);
        #pragma unroll
        for (int i = 0; i < 16; ++i) {
            int e = w * 16 + i;
            int rcv = rl_i(rAll, e);
            if (rcv != cur) {
                flush2(agS2 + cur * 128, lane, accS);
                accS = 0.f; cur = rcv;
            }
            accS += trw[i * 64 + ((lane + 4 * i) & 63)] * sreg[i];
        }
        flush2(agS2 + cur * 128, lane, accS);
    }

    // ===== chunk B: channels 64..127 (mB -> agV2 lo) =====
    #pragma unroll
    for (int nt = 0; nt < 4; ++nt) {
        int c = nt * 16 + nl;
        int ng = 64 + c;
        const unsigned short* wh = w3h + ng * 64 + q * 8;
        const unsigned short* wl = w3l + ng * 64 + q * 8;
        bf16x8 bh0 = *(const bf16x8*)wh;
        bf16x8 bh1 = *(const bf16x8*)(wh + 32);
        bf16x8 bl0 = *(const bf16x8*)wl;
        bf16x8 bl1 = *(const bf16x8*)(wl + 32);
        f32x4 a = {0.f, 0.f, 0.f, 0.f};
        a = __builtin_amdgcn_mfma_f32_16x16x32_bf16(ah0, bh0, a, 0, 0, 0);
        a = __builtin_amdgcn_mfma_f32_16x16x32_bf16(ah1, bh1, a, 0, 0, 0);
        a = __builtin_amdgcn_mfma_f32_16x16x32_bf16(ah0, bl0, a, 0, 0, 0);
        a = __builtin_amdgcn_mfma_f32_16x16x32_bf16(ah1, bl1, a, 0, 0, 0);
        a = __builtin_amdgcn_mfma_f32_16x16x32_bf16(al0, bh0, a, 0, 0, 0);
        a = __builtin_amdgcn_mfma_f32_16x16x32_bf16(al1, bh1, a, 0, 0, 0);
        #pragma unroll
        for (int r = 0; r < 4; ++r) {
            int li = q * 4 + r;
            trw[li * 64 + ((c + 4 * li) & 63)] = a[r];
        }
    }
    {
        float b0 = 0.f, b1 = 0.f, b2 = 0.f;
        int cur = rl_i(rAll, w * 16);
        #pragma unroll
        for (int i = 0; i < 16; ++i) {
            int e = w * 16 + i;
            int rcv = rl_i(rAll, e);
            if (rcv != cur) {
                flush2(agV2 + cur * 384,       lane, b0);
                flush2(agV2 + cur * 384 + 128, lane, b1);
                flush2(agV2 + cur * 384 + 256, lane, b2);
                b0 = b1 = b2 = 0.f; cur = rcv;
            }
            float msg = trw[i * 64 + ((lane + 4 * i) & 63)] * sreg[i];
            b0 += msg * rl_f(y0A, e);
            b1 += msg * rl_f(y1A, e);
            b2 += msg * rl_f(y2A, e);
        }
        flush2(agV2 + cur * 384,       lane, b0);
        flush2(agV2 + cur * 384 + 128, lane, b1);
        flush2(agV2 + cur * 384 + 256, lane, b2);
    }

    // ===== vUp2 preload (sreg dead -> registers reused) =====
    float vr0[16], vr1[16], vr2[16];
    #pragma unroll
    for (int i = 0; i < 16; ++i) {
        int snd = rl_i(sAll, w * 16 + i);
        vr0[i] = __half2float(vUp2[snd * 192 +       lane]);
        vr1[i] = __half2float(vUp2[snd * 192 +  64 + lane]);
        vr2[i] = __half2float(vUp2[snd * 192 + 128 + lane]);
    }

    // ===== chunk C: channels 128..191 (mC -> agV2 hi) =====
    #pragma unroll
    for (int nt = 0; nt < 4; ++nt) {
        int c = nt * 16 + nl;
        int ng = 128 + c;
        const unsigned short* wh = w3h + ng * 64 + q * 8;
        const unsigned short* wl = w3l + ng * 64 + q * 8;
        bf16x8 bh0 = *(const bf16x8*)wh;
        bf16x8 bh1 = *(const bf16x8*)(wh + 32);
        bf16x8 bl0 = *(const bf16x8*)wl;
        bf16x8 bl1 = *(const bf16x8*)(wl + 32);
        f32x4 a = {0.f, 0.f, 0.f, 0.f};
        a = __builtin_amdgcn_mfma_f32_16x16x32_bf16(ah0, bh0, a, 0, 0, 0);
        a = __builtin_amdgcn_mfma_f32_16x16x32_bf16(ah1, bh1, a, 0, 0, 0);
        a = __builtin_amdgcn_mfma_f32_16x16x32_bf16(ah0, bl0, a, 0, 0, 0);
        a = __builtin_amdgcn_mfma_f32_16x16x32_bf16(ah1, bl1, a, 0, 0, 0);
        a = __builtin_amdgcn_mfma_f32_16x16x32_bf16(al0, bh0, a, 0, 0, 0);
        a = __builtin_amdgcn_mfma_f32_16x16x32_bf16(al1, bh1, a, 0, 0, 0);
        #pragma unroll
        for (int r = 0; r < 4; ++r) {
            int li = q * 4 + r;
            trw[li * 64 + ((c + 4 * li) & 63)] = a[r];
        }
    }
    {
        float c0 = 0.f, c1 = 0.f, c2 = 0.f;
        int cur = rl_i(rAll, w * 16);
        #pragma unroll
        for (int i = 0; i < 16; ++i) {
            int e = w * 16 + i;
            int rcv = rl_i(rAll, e);
            if (rcv != cur) {
                flush2(agV2 + cur * 384 +  64, lane, c0);
                flush2(agV2 + cur * 384 + 192, lane, c1);
                flush2(agV2 + cur * 384 + 320, lane, c2);
                c0 = c1 = c2 = 0.f; cur = rcv;
            }
            float tvC = trw[i * 64 + ((lane + 4 * i) & 63)];
            c0 += tvC * vr0[i];
            c1 += tvC * vr1[i];
            c2 += tvC * vr2[i];
        }
        flush2(agV2 + cur * 384 +  64, lane, c0);
        flush2(agV2 + cur * 384 + 192, lane, c1);
        flush2(agV2 + cur * 384 + 320, lane, c2);
    }

    // ===== chunk D: channels 192..255 (mD -> agS2 hi) =====
    #pragma unroll
    for (int nt = 0; nt < 4; ++nt) {
        int c = nt * 16 + nl;
        int ng = 192 + c;
        const unsigned short* wh = w3h + ng * 64 + q * 8;
        const unsigned short* wl = w3l + ng * 64 + q * 8;
        bf16x8 bh0 = *(const bf16x8*)wh;
        bf16x8 bh1 = *(const bf16x8*)(wh + 32);
        bf16x8 bl0 = *(const bf16x8*)wl;
        bf16x8 bl1 = *(const bf16x8*)(wl + 32);
        f32x4 a = {0.f, 0.f, 0.f, 0.f};
        a = __builtin_amdgcn_mfma_f32_16x16x32_bf16(ah0, bh0, a, 0, 0, 0);
        a = __builtin_amdgcn_mfma_f32_16x16x32_bf16(ah1, bh1, a, 0, 0, 0);
        a = __builtin_amdgcn_mfma_f32_16x16x32_bf16(ah0, bl0, a, 0, 0, 0);
        a = __builtin_amdgcn_mfma_f32_16x16x32_bf16(ah1, bl1, a, 0, 0, 0);
        a = __builtin_amdgcn_mfma_f32_16x16x32_bf16(al0, bh0, a, 0, 0, 0);
        a = __builtin_amdgcn_mfma_f32_16x16x32_bf16(al1, bh1, a, 0, 0, 0);
        #pragma unroll
        for (int r = 0; r < 4; ++r) {
            int li = q * 4 + r;
            trw[li * 64 + ((c + 4 * li) & 63)] = a[r];
        }
    }
    {
        float accD = 0.f;
        int cur = rl_i(rAll, w * 16);
        #pragma unroll
        for (int i = 0; i < 16; ++i) {
            int e = w * 16 + i;
            int rcv = rl_i(rAll, e);
            if (rcv != cur) {
                flush2(agS2 + cur * 128 + 64, lane, accD);
                accD = 0.f; cur = rcv;
            }
            float tvD = trw[i * 64 + ((lane + 4 * i) & 63)];
            float dotvy = vr0[i] * rl_f(y0A, e) + vr1[i] * rl_f(y1A, e)
                        + vr2[i] * rl_f(y2A, e);
            accD += tvD * dotvy * 0.577350269189626f;
        }
        flush2(agS2 + cur * 128 + 64, lane, accD);
    }
}

// ---------------- node out ----------------
__global__ __launch_bounds__(256) void k_node_out(
    const float* __restrict__ L2s, const float* __restrict__ L2v,
    const __half* __restrict__ agS2, const __half* __restrict__ agV2,
    const float* __restrict__ skS2, const float* __restrict__ skV2,
    float* __restrict__ out)
{
    int lane = threadIdx.x & 63, wv = threadIdx.x >> 6;
    int n = blockIdx.x * 4 + wv;
    __shared__ __align__(16) float aS[4][128];
    __shared__ __align__(16) float aV[4][3][128];

    aS[wv][lane]      = __half2float(agS2[n * 128 + lane]);
    aS[wv][64 + lane] = __half2float(agS2[n * 128 + 64 + lane]);
    #pragma unroll
    for (int i = 0; i < 3; ++i) {
        aV[wv][i][lane]      = __half2float(agV2[n * 384 + i * 128 + lane]);
        aV[wv][i][64 + lane] = __half2float(agV2[n * 384 + i * 128 + 64 + lane]);
    }
    __syncthreads();

    float s2 = skS2[n * 64 + lane];
    #pragma unroll 8
    for (int u = 0; u < 128; ++u) s2 += aS[wv][u] * L2s[u * 64 + lane];
    float v2[3];
    #pragma unroll
    for (int i = 0; i < 3; ++i) v2[i] = skV2[n * 192 + i * 64 + lane];
    #pragma unroll 8
    for (int u = 0; u < 128; ++u) {
        float w = L2v[u * 64 + lane];
        v2[0] += aV[wv][0][u] * w;
        v2[1] += aV[wv][1][u] * w;
        v2[2] += aV[wv][2][u] * w;
    }
    out[(size_t)n * 256 + lane] = s2;
    #pragma unroll
    for (int i = 0; i < 3; ++i)
        out[(size_t)n * 256 + 64 + lane * 3 + i] = v2[i];
}

// ---------------- host launcher ----------------
extern "C" void kernel_launch(void* const* d_in, const int* in_sizes, int n_in,
                              void* d_out, int out_size, void* d_ws, size_t ws_size,
                              hipStream_t stream)
{
    (void)in_sizes; (void)n_in; (void)out_size; (void)ws_size;
    const float* positions  = (const float*)d_in[0];
    const float* node_attrs = (const float*)d_in[1];
    const int*   edge_index = (const int*)d_in[2];
    const float* shifts     = (const float*)d_in[3];
    const float* W_embed    = (const float*)d_in[4];
    const float* R1W1 = (const float*)d_in[5];
    const float* R1W2 = (const float*)d_in[6];
    const float* R1W3 = (const float*)d_in[7];
    const float* U1s  = (const float*)d_in[8];
    const float* L1s  = (const float*)d_in[9];
    const float* L1v  = (const float*)d_in[10];
    const float* K1s  = (const float*)d_in[11];
    const float* R2W1 = (const float*)d_in[12];
    const float* R2W2 = (const float*)d_in[13];
    const float* R2W3 = (const float*)d_in[14];
    const float* U2s  = (const float*)d_in[15];
    const float* U2v  = (const float*)d_in[16];
    const float* L2s  = (const float*)d_in[17];
    const float* L2v  = (const float*)d_in[18];
    const float* K2s  = (const float*)d_in[19];
    const float* K2v  = (const float*)d_in[20];

    float* wsf = (float*)d_ws;
    int*   wsi = (int*)(wsf + OFF_INT);
    int* hist   = wsi;
    int* cursor = wsi + 20000;
    int* sorted = wsi + 40000;
    unsigned short* wsh = (unsigned short*)(wsi + 360000);
    const unsigned short* w3a_hi = wsh;
    const unsigned short* w3a_lo = wsh + 8192;
    const unsigned short* w3b_hi = wsh + 16384;
    const unsigned short* w3b_lo = wsh + 32768;

    __half* sUp1h = (__half*)(wsf + OFF_SUP1);
    __half* sUp2h = (__half*)(wsf + OFF_SUP2);
    __half* vUp2h = (__half*)(wsf + OFF_VUP2);
    __half* agS1h = (__half*)(wsf + OFF_AGS1);
    __half* agV1h = (__half*)(wsf + OFF_AGV1);
    __half* agS2h = (__half*)(wsf + OFF_AGS2);
    __half* agV2h = (__half*)(wsf + OFF_AGV2);

    // zero agS1 [2.56MB] .. agV1 [7.68MB] (covers the gap; all dead space)
    hipMemsetAsync(wsf + OFF_AGS1, 0,
                   (size_t)NC * sizeof(float) + (size_t)20000 * 192 * sizeof(__half),
                   stream);
    hipMemsetAsync(hist, 0, 20000 * sizeof(int), stream);

    k_wsplit<<<96, 256, 0, stream>>>(R1W3, R2W3, wsh);
    k_hist<<<NEDGES / 256, 256, 0, stream>>>(edge_index, hist);
    k_scan<<<1, 1024, 0, stream>>>(hist, cursor);
    k_scatter<<<NEDGES / 256, 256, 0, stream>>>(edge_index, cursor, sorted);

    k_node_pre<<<NNODES / 4, 256, 0, stream>>>(node_attrs, W_embed, U1s, sUp1h);
    k_edge1<<<NEDGES / 64, 256, 0, stream>>>(positions, edge_index, shifts, sorted,
                                             R1W1, R1W2, w3a_hi, w3a_lo,
                                             sUp1h, agS1h, agV1h);
    k_node_mid<<<NNODES / 4, 256, 0, stream>>>(node_attrs, W_embed, K1s, L1s, L1v,
                                               U2s, U2v, K2s, K2v,
                                               agS1h, agV1h,
                                               sUp2h, vUp2h,
                                               wsf + OFF_SKS2, wsf + OFF_SKV2);
    // zero agS2 [5.12MB] .. agV2 [15.36MB] (covers the gap; all dead space)
    hipMemsetAsync(wsf + OFF_AGS2, 0,
                   (size_t)2 * NC * sizeof(float) + (size_t)20000 * 384 * sizeof(__half),
                   stream);
    k_edge2<<<NEDGES / 64, 256, 0, stream>>>(positions, edge_index, shifts, sorted,
                                             R2W1, R2W2, w3b_hi, w3b_lo,
                                             sUp2h, vUp2h,
                                             agS2h, agV2h);
    k_node_out<<<NNODES / 4, 256, 0, stream>>>(L2s, L2v, agS2h, agV2h,
                                               wsf + OFF_SKS2, wsf + OFF_SKV2,
                                               (float*)d_out);
}

// Round 11
// 609.890 us; speedup vs baseline: 1.0247x; 1.0247x over previous
//
#include <hip/hip_runtime.h>
#include <hip/hip_fp16.h>

// ---------------- problem constants ----------------
#define NNODES 20000
#define NEDGES 320000
#define NELEM  10
#define NC     (NNODES * 64)   // 1,280,000

// ---------------- phase-overlaid ws layout (float offsets) ----------------
#define OFF_SUP1 ((size_t)0)
#define OFF_AGS1 ((size_t)1 * NC)
#define OFF_AGV1 ((size_t)2 * NC)
#define OFF_AGS2 ((size_t)0)
#define OFF_AGV2 ((size_t)2 * NC)
#define OFF_SUP2 ((size_t)8 * NC)
#define OFF_VUP2 ((size_t)9 * NC)
#define OFF_SKS2 ((size_t)12 * NC)
#define OFF_SKV2 ((size_t)13 * NC)
#define OFF_INT  ((size_t)16 * NC)
// sUp1/sUp2/vUp2 stored fp16 (half of each NC-float slot).
// bf16 split W3 (ushort units) after the 360000 ints:
//   w3a_hi [128][64] @0, w3a_lo @8192, w3b_hi [256][64] @16384, w3b_lo @32768

// k_edge1 smem overlay (38656 B -> 4 blocks/CU):
//   [0,768) ysh | [768,1024) ssh | [1024,1280) rsh
//   [1280,17920) h1sh f32[64][65]   (tr 4x[16][64] overlays after A2)
//   [17920,36352) h2buf u16[2][64][72] | [36352,38656) fsh f32[64][9]
#define SMEM1_BYTES 38656
// k_edge2 smem overlay (52480 B -> 3 blocks/CU):
//   [0,768) ysh | [768,1024) ssh | [1024,1280) rsh
//   [1280,17920) h1sh f32[64][65]   (tr 4x[16][128] overlays after A2, to 34048)
//   [17920,20224) fsh f32[64][9] | [34048,52480) h2buf u16[2][64][72]
#define SMEM2_BYTES 52480

// XCD-aware block swizzle: grid 5000 = 8*625, bijective contiguous-chunk map.
__device__ __forceinline__ int xcd_swz(int bid) {
    return (bid & 7) * 625 + (bid >> 3);
}

typedef __attribute__((ext_vector_type(8))) short bf16x8;
typedef __attribute__((ext_vector_type(4))) float f32x4;

__device__ __forceinline__ float silu(float x) { return x / (1.0f + __expf(-x)); }
__device__ __forceinline__ int rfl(int v) { return __builtin_amdgcn_readfirstlane(v); }
__device__ __forceinline__ int rl_i(int v, int l) { return __builtin_amdgcn_readlane(v, l); }
__device__ __forceinline__ float rl_f(float v, int l) {
    return __int_as_float(__builtin_amdgcn_readlane(__float_as_int(v), l));
}
// split two f32 into packed bf16 hi-pair (x) and lo-pair (y), round-to-nearest
__device__ __forceinline__ uint2 split2(float x0, float x1) {
    unsigned int b0 = __float_as_uint(x0), b1 = __float_as_uint(x1);
    unsigned int h0 = (b0 + 0x7FFF + ((b0 >> 16) & 1)) & 0xFFFF0000u;
    unsigned int h1 = (b1 + 0x7FFF + ((b1 >> 16) & 1)) & 0xFFFF0000u;
    unsigned int l0 = __float_as_uint(x0 - __uint_as_float(h0));
    unsigned int l1 = __float_as_uint(x1 - __uint_as_float(h1));
    unsigned int hi = (h0 >> 16) | (h1 & 0xFFFF0000u);
    unsigned int lo = ((l0 + 0x7FFF + ((l0 >> 16) & 1)) >> 16)
                    | ((l1 + 0x7FFF + ((l1 >> 16) & 1)) & 0xFFFF0000u);
    return make_uint2(hi, lo);
}

// ---------------- weight split: W3 -> transposed bf16 hi/lo ----------------
__global__ __launch_bounds__(256) void k_wsplit(
    const float* __restrict__ W3a, const float* __restrict__ W3b,
    unsigned short* __restrict__ out)
{
    int t = blockIdx.x * 256 + threadIdx.x;   // 24576 total
    float x; unsigned short *ph, *pl; int idx;
    if (t < 8192) {
        int n = t >> 6, k = t & 63;
        x = W3a[k * 128 + n]; ph = out; pl = out + 8192; idx = n * 64 + k;
    } else {
        int u = t - 8192; int n = u >> 6, k = u & 63;
        x = W3b[k * 256 + n]; ph = out + 16384; pl = out + 32768; idx = n * 64 + k;
    }
    unsigned int b = __float_as_uint(x);
    unsigned int h = (b + 0x7FFF + ((b >> 16) & 1)) & 0xFFFF0000u;
    unsigned int r = __float_as_uint(x - __uint_as_float(h));
    ph[idx] = (unsigned short)(h >> 16);
    pl[idx] = (unsigned short)((r + 0x7FFF + ((r >> 16) & 1)) >> 16);
}

// ---------------- sort by rcv ----------------
__global__ __launch_bounds__(256) void k_hist(const int* __restrict__ eidx,
                                              int* __restrict__ hist)
{
    int e = blockIdx.x * 256 + threadIdx.x;
    atomicAdd(&hist[eidx[NEDGES + e]], 1);
}

__global__ __launch_bounds__(1024) void k_scan(const int* __restrict__ hist,
                                               int* __restrict__ cursor)
{
    __shared__ int wsum[16];
    __shared__ int gbase;
    int tid = threadIdx.x;
    int lane = tid & 63, wvid = tid >> 6;
    if (tid == 0) gbase = 0;
    __syncthreads();
    for (int seg = 0; seg < 20; ++seg) {
        int i = seg * 1024 + tid;
        int v = (i < NNODES) ? hist[i] : 0;
        int s = v;
        #pragma unroll
        for (int d = 1; d < 64; d <<= 1) {
            int t = __shfl_up(s, d, 64);
            if (lane >= d) s += t;
        }
        if (lane == 63) wsum[wvid] = s;
        __syncthreads();
        if (wvid == 0) {
            int w = (lane < 16) ? wsum[lane] : 0;
            #pragma unroll
            for (int d = 1; d < 16; d <<= 1) {
                int t = __shfl_up(w, d, 64);
                if (lane >= d) w += t;
            }
            if (lane < 16) wsum[lane] = w;
        }
        __syncthreads();
        int wbase = (wvid == 0) ? 0 : wsum[wvid - 1];
        if (i < NNODES) cursor[i] = gbase + wbase + s - v;
        int segtot = wsum[15];
        __syncthreads();
        if (tid == 0) gbase += segtot;
    }
}

__global__ __launch_bounds__(256) void k_scatter(const int* __restrict__ eidx,
                                                 int* __restrict__ cursor,
                                                 int* __restrict__ sorted)
{
    int e = blockIdx.x * 256 + threadIdx.x;
    int pos = atomicAdd(&cursor[eidx[NEDGES + e]], 1);
    sorted[pos] = e;
}

// ---------------- node pre ----------------
__global__ __launch_bounds__(256) void k_node_pre(
    const float* __restrict__ attrs, const float* __restrict__ Wemb,
    const float* __restrict__ U1s, __half* __restrict__ sUp1)
{
    int lane = threadIdx.x & 63, wv = threadIdx.x >> 6;
    int n = blockIdx.x * 4 + wv;
    __shared__ __align__(16) float s0sh[4][64];
    float s0 = 0.f;
    #pragma unroll
    for (int v = 0; v < NELEM; ++v) s0 += attrs[n * NELEM + v] * Wemb[v * 64 + lane];
    s0sh[wv][lane] = s0;
    __syncthreads();
    float a = 0.f;
    #pragma unroll 8
    for (int k = 0; k < 64; ++k) a += s0sh[wv][k] * U1s[k * 64 + lane];
    sUp1[n * 64 + lane] = __float2half_rn(a);
}

// ---------------- edge block 1: chunked, 4/CU, hoisted gathers -------------
__global__ __launch_bounds__(256, 4) void k_edge1(
    const float* __restrict__ pos, const int* __restrict__ eidx,
    const float* __restrict__ shf, const int* __restrict__ sorted,
    const float* __restrict__ W1, const float* __restrict__ W2,
    const unsigned short* __restrict__ w3h, const unsigned short* __restrict__ w3l,
    const __half* __restrict__ sUp1,
    float* __restrict__ agS1, float* __restrict__ agV1)
{
    __shared__ __align__(16) char smem[SMEM1_BYTES];
    float (*ysh)[3]   = (float (*)[3])(smem);
    int*  ssh         = (int*)(smem + 768);
    int*  rsh         = (int*)(smem + 1024);
    float (*h1sh)[65] = (float (*)[65])(smem + 1280);
    unsigned short (*h2buf)[64][72] = (unsigned short (*)[64][72])(smem + 17920);
    float (*fsh)[9]   = (float (*)[9])(smem + 36352);

    const int tid = threadIdx.x;
    const int lane = tid & 63;
    const int w = rfl(tid >> 6);
    const int e0 = xcd_swz(blockIdx.x) * 64;

    // ---- stage: 4 threads per edge ----
    {
        int e = tid >> 2, sub = tid & 3;
        int sid = sorted[e0 + e];
        int snd = eidx[sid], rcv = eidx[NEDGES + sid];
        float dx = pos[snd * 3 + 0] - pos[rcv * 3 + 0] + shf[(size_t)sid * 3 + 0];
        float dy = pos[snd * 3 + 1] - pos[rcv * 3 + 1] + shf[(size_t)sid * 3 + 1];
        float dz = pos[snd * 3 + 2] - pos[rcv * 3 + 2] + shf[(size_t)sid * 3 + 2];
        float len = sqrtf(dx * dx + dy * dy + dz * dz + 1e-12f);
        float inv = 1.0f / len;
        float u = len * 0.2f;
        float u2 = u * u, u4 = u2 * u2, u5 = u4 * u, u6 = u5 * u, u7 = u6 * u;
        float cut = (u < 1.0f) ? (1.0f - 21.0f * u5 + 35.0f * u6 - 15.0f * u7) : 0.0f;
        float s = 0.632455532033676f * inv * cut;
        #pragma unroll
        for (int kk = 0; kk < 2; ++kk) {
            int k = sub * 2 + kk;
            fsh[e][k] = s * sinf((float)(k + 1) * 0.628318530717959f * len);
        }
        if (sub == 0) {
            ssh[e] = snd; rsh[e] = rcv;
            ysh[e][0] = 1.73205080756888f * dx * inv;
            ysh[e][1] = 1.73205080756888f * dy * inv;
            ysh[e][2] = 1.73205080756888f * dz * inv;
        }
    }
    __syncthreads();

    const int rAll = rsh[lane];
    const int sAll = ssh[lane];
    const float y0A = ysh[lane][0], y1A = ysh[lane][1], y2A = ysh[lane][2];

    // ---- hoisted gathers: issue now, consume after A1+A2 (latency hidden) --
    __half sregh[16];
    #pragma unroll
    for (int i = 0; i < 16; ++i)
        sregh[i] = sUp1[rl_i(sAll, w * 16 + i) * 64 + lane];

    // ---- A1: 8->64 ----
    {
        float f[8];
        #pragma unroll
        for (int k = 0; k < 8; ++k) f[k] = fsh[lane][k];
        const float* __restrict__ w1b = W1 + w * 16;
        #pragma unroll
        for (int j = 0; j < 16; ++j) {
            float a = 0.f;
            #pragma unroll
            for (int k = 0; k < 8; ++k) a = fmaf(f[k], w1b[k * 64 + j], a);
            h1sh[lane][w * 16 + j] = silu(a);
        }
    }
    __syncthreads();

    // ---- A2: 64->64, split-bf16 epilogue ----
    {
        const float2* __restrict__ w2b = (const float2*)W2 + w * 8;
        float2 acc[8];
        #pragma unroll
        for (int j = 0; j < 8; ++j) acc[j] = make_float2(0.f, 0.f);
        for (int k = 0; k < 64; ++k) {
            float h = h1sh[lane][k];
            const float2* __restrict__ wk = w2b + k * 32;
            #pragma unroll
            for (int j = 0; j < 8; ++j) {
                float2 wv = wk[j];
                acc[j].x = fmaf(h, wv.x, acc[j].x);
                acc[j].y = fmaf(h, wv.y, acc[j].y);
            }
        }
        #pragma unroll
        for (int j = 0; j < 8; ++j) {
            uint2 p = split2(silu(acc[j].x), silu(acc[j].y));
            *(unsigned int*)&h2buf[0][lane][w * 16 + 2 * j] = p.x;
            *(unsigned int*)&h2buf[1][lane][w * 16 + 2 * j] = p.y;
        }
    }
    __syncthreads();   // h1sh dead; tr overlays it (wave-local from here)

    // ---- B: wave w owns edges [w*16, w*16+16), 2 chunks of 64 channels ----
    const int q = lane >> 4, nl = lane & 15;
    float* trw = (float*)(smem + 1280) + w * 1024;   // [16][64]

    const unsigned short* ar = &h2buf[0][w * 16 + nl][0];
    const unsigned short* al = &h2buf[1][w * 16 + nl][0];
    bf16x8 ah0 = *(const bf16x8*)(ar + q * 8);
    bf16x8 ah1 = *(const bf16x8*)(ar + 32 + q * 8);
    bf16x8 al0 = *(const bf16x8*)(al + q * 8);
    bf16x8 al1 = *(const bf16x8*)(al + 32 + q * 8);

    // ===== chunk 0: channels 0..63 (mA -> agS1) =====
    #pragma unroll
    for (int nt = 0; nt < 4; ++nt) {
        int c = nt * 16 + nl;
        const unsigned short* wh = w3h + c * 64 + q * 8;
        const unsigned short* wl = w3l + c * 64 + q * 8;
        bf16x8 bh0 = *(const bf16x8*)wh;
        bf16x8 bh1 = *(const bf16x8*)(wh + 32);
        bf16x8 bl0 = *(const bf16x8*)wl;
        bf16x8 bl1 = *(const bf16x8*)(wl + 32);
        f32x4 a = {0.f, 0.f, 0.f, 0.f};
        a = __builtin_amdgcn_mfma_f32_16x16x32_bf16(ah0, bh0, a, 0, 0, 0);
        a = __builtin_amdgcn_mfma_f32_16x16x32_bf16(ah1, bh1, a, 0, 0, 0);
        a = __builtin_amdgcn_mfma_f32_16x16x32_bf16(ah0, bl0, a, 0, 0, 0);
        a = __builtin_amdgcn_mfma_f32_16x16x32_bf16(ah1, bl1, a, 0, 0, 0);
        a = __builtin_amdgcn_mfma_f32_16x16x32_bf16(al0, bh0, a, 0, 0, 0);
        a = __builtin_amdgcn_mfma_f32_16x16x32_bf16(al1, bh1, a, 0, 0, 0);
        #pragma unroll
        for (int r = 0; r < 4; ++r) {
            int li = q * 4 + r;
            trw[li * 64 + ((c + 4 * li) & 63)] = a[r];
        }
    }
    {
        float accS = 0.f;
        int cur = rl_i(rAll, w * 16);
        #pragma unroll
        for (int i = 0; i < 16; ++i) {
            int e = w * 16 + i;
            int rcv = rl_i(rAll, e);
            if (rcv != cur) {
                unsafeAtomicAdd(&agS1[cur * 64 + lane], accS);
                accS = 0.f; cur = rcv;
            }
            accS += trw[i * 64 + ((lane + 4 * i) & 63)] * __half2float(sregh[i]);
        }
        unsafeAtomicAdd(&agS1[cur * 64 + lane], accS);
    }

    // ===== chunk 1: channels 64..127 (mB -> agV1) =====
    #pragma unroll
    for (int nt = 0; nt < 4; ++nt) {
        int c = nt * 16 + nl;
        int ng = 64 + c;
        const unsigned short* wh = w3h + ng * 64 + q * 8;
        const unsigned short* wl = w3l + ng * 64 + q * 8;
        bf16x8 bh0 = *(const bf16x8*)wh;
        bf16x8 bh1 = *(const bf16x8*)(wh + 32);
        bf16x8 bl0 = *(const bf16x8*)wl;
        bf16x8 bl1 = *(const bf16x8*)(wl + 32);
        f32x4 a = {0.f, 0.f, 0.f, 0.f};
        a = __builtin_amdgcn_mfma_f32_16x16x32_bf16(ah0, bh0, a, 0, 0, 0);
        a = __builtin_amdgcn_mfma_f32_16x16x32_bf16(ah1, bh1, a, 0, 0, 0);
        a = __builtin_amdgcn_mfma_f32_16x16x32_bf16(ah0, bl0, a, 0, 0, 0);
        a = __builtin_amdgcn_mfma_f32_16x16x32_bf16(ah1, bl1, a, 0, 0, 0);
        a = __builtin_amdgcn_mfma_f32_16x16x32_bf16(al0, bh0, a, 0, 0, 0);
        a = __builtin_amdgcn_mfma_f32_16x16x32_bf16(al1, bh1, a, 0, 0, 0);
        #pragma unroll
        for (int r = 0; r < 4; ++r) {
            int li = q * 4 + r;
            trw[li * 64 + ((c + 4 * li) & 63)] = a[r];
        }
    }
    {
        float b0 = 0.f, b1 = 0.f, b2 = 0.f;
        int cur = rl_i(rAll, w * 16);
        #pragma unroll
        for (int i = 0; i < 16; ++i) {
            int e = w * 16 + i;
            int rcv = rl_i(rAll, e);
            if (rcv != cur) {
                unsafeAtomicAdd(&agV1[cur * 192 +       lane], b0);
                unsafeAtomicAdd(&agV1[cur * 192 +  64 + lane], b1);
                unsafeAtomicAdd(&agV1[cur * 192 + 128 + lane], b2);
                b0 = b1 = b2 = 0.f; cur = rcv;
            }
            float msg = trw[i * 64 + ((lane + 4 * i) & 63)] * __half2float(sregh[i]);
            b0 += msg * rl_f(y0A, e);
            b1 += msg * rl_f(y1A, e);
            b2 += msg * rl_f(y2A, e);
        }
        unsafeAtomicAdd(&agV1[cur * 192 +       lane], b0);
        unsafeAtomicAdd(&agV1[cur * 192 +  64 + lane], b1);
        unsafeAtomicAdd(&agV1[cur * 192 + 128 + lane], b2);
    }
}

// ---------------- node mid ----------------
__global__ __launch_bounds__(256) void k_node_mid(
    const float* __restrict__ attrs, const float* __restrict__ Wemb,
    const float* __restrict__ K1s, const float* __restrict__ L1s,
    const float* __restrict__ L1v,
    const float* __restrict__ U2s, const float* __restrict__ U2v,
    const float* __restrict__ K2s, const float* __restrict__ K2v,
    const float* __restrict__ agS1, const float* __restrict__ agV1,
    __half* __restrict__ sUp2, __half* __restrict__ vUp2,
    float* __restrict__ skS2, float* __restrict__ skV2)
{
    int lane = threadIdx.x & 63, wv = threadIdx.x >> 6;
    int n = blockIdx.x * 4 + wv;
    __shared__ float aSsh[4][64];
    __shared__ float aVsh[4][3][64];
    __shared__ float s0sh[4][64];
    __shared__ float s1sh[4][64];
    __shared__ float v1sh[4][3][64];

    int sp = 0;
    #pragma unroll
    for (int v = 0; v < NELEM; ++v) if (attrs[n * NELEM + v] > 0.5f) sp = v;
    aSsh[wv][lane] = agS1[n * 64 + lane];
    #pragma unroll
    for (int i = 0; i < 3; ++i) aVsh[wv][i][lane] = agV1[n * 192 + i * 64 + lane];
    s0sh[wv][lane] = Wemb[sp * 64 + lane];
    __syncthreads();

    float s1 = 0.f;
    #pragma unroll 8
    for (int k = 0; k < 64; ++k) s1 += aSsh[wv][k] * L1s[k * 64 + lane];
    #pragma unroll 8
    for (int k = 0; k < 64; ++k) s1 += s0sh[wv][k] * K1s[(k * NELEM + sp) * 64 + lane];
    float v1[3] = {0.f, 0.f, 0.f};
    #pragma unroll 8
    for (int k = 0; k < 64; ++k) {
        float w = L1v[k * 64 + lane];
        v1[0] += aVsh[wv][0][k] * w;
        v1[1] += aVsh[wv][1][k] * w;
        v1[2] += aVsh[wv][2][k] * w;
    }
    s1sh[wv][lane] = s1;
    #pragma unroll
    for (int i = 0; i < 3; ++i) v1sh[wv][i][lane] = v1[i];
    __syncthreads();

    float su = 0.f, ks = 0.f;
    float vu[3] = {0.f, 0.f, 0.f}, kv[3] = {0.f, 0.f, 0.f};
    #pragma unroll 8
    for (int k = 0; k < 64; ++k) su += s1sh[wv][k] * U2s[k * 64 + lane];
    #pragma unroll 8
    for (int k = 0; k < 64; ++k) ks += s1sh[wv][k] * K2s[(k * NELEM + sp) * 64 + lane];
    #pragma unroll 8
    for (int k = 0; k < 64; ++k) {
        float w = U2v[k * 64 + lane];
        vu[0] += v1sh[wv][0][k] * w;
        vu[1] += v1sh[wv][1][k] * w;
        vu[2] += v1sh[wv][2][k] * w;
    }
    #pragma unroll 8
    for (int k = 0; k < 64; ++k) {
        float w = K2v[(k * NELEM + sp) * 64 + lane];
        kv[0] += v1sh[wv][0][k] * w;
        kv[1] += v1sh[wv][1][k] * w;
        kv[2] += v1sh[wv][2][k] * w;
    }
    sUp2[n * 64 + lane] = __float2half_rn(su);
    skS2[n * 64 + lane] = ks;
    #pragma unroll
    for (int i = 0; i < 3; ++i) {
        vUp2[n * 192 + i * 64 + lane] = __float2half_rn(vu[i]);
        skV2[n * 192 + i * 64 + lane] = kv[i];
    }
}

// ---------------- edge block 2: two-pass, 3/CU, hoisted gathers ------------
__global__ __launch_bounds__(256, 3) void k_edge2(
    const float* __restrict__ pos, const int* __restrict__ eidx,
    const float* __restrict__ shf, const int* __restrict__ sorted,
    const float* __restrict__ W1, const float* __restrict__ W2,
    const unsigned short* __restrict__ w3h, const unsigned short* __restrict__ w3l,
    const __half* __restrict__ sUp2, const __half* __restrict__ vUp2,
    float* __restrict__ agS2, float* __restrict__ agV2)
{
    __shared__ __align__(16) char smem[SMEM2_BYTES];
    float (*ysh)[3]   = (float (*)[3])(smem);
    int*  ssh         = (int*)(smem + 768);
    int*  rsh         = (int*)(smem + 1024);
    float (*h1sh)[65] = (float (*)[65])(smem + 1280);
    float (*fsh)[9]   = (float (*)[9])(smem + 17920);
    unsigned short (*h2buf)[64][72] = (unsigned short (*)[64][72])(smem + 34048);

    const int tid = threadIdx.x;
    const int lane = tid & 63;
    const int w = rfl(tid >> 6);
    const int e0 = xcd_swz(blockIdx.x) * 64;

    // ---- stage: 4 threads per edge ----
    {
        int e = tid >> 2, sub = tid & 3;
        int sid = sorted[e0 + e];
        int snd = eidx[sid], rcv = eidx[NEDGES + sid];
        float dx = pos[snd * 3 + 0] - pos[rcv * 3 + 0] + shf[(size_t)sid * 3 + 0];
        float dy = pos[snd * 3 + 1] - pos[rcv * 3 + 1] + shf[(size_t)sid * 3 + 1];
        float dz = pos[snd * 3 + 2] - pos[rcv * 3 + 2] + shf[(size_t)sid * 3 + 2];
        float len = sqrtf(dx * dx + dy * dy + dz * dz + 1e-12f);
        float inv = 1.0f / len;
        float u = len * 0.2f;
        float u2 = u * u, u4 = u2 * u2, u5 = u4 * u, u6 = u5 * u, u7 = u6 * u;
        float cut = (u < 1.0f) ? (1.0f - 21.0f * u5 + 35.0f * u6 - 15.0f * u7) : 0.0f;
        float s = 0.632455532033676f * inv * cut;
        #pragma unroll
        for (int kk = 0; kk < 2; ++kk) {
            int k = sub * 2 + kk;
            fsh[e][k] = s * sinf((float)(k + 1) * 0.628318530717959f * len);
        }
        if (sub == 0) {
            ssh[e] = snd; rsh[e] = rcv;
            ysh[e][0] = 1.73205080756888f * dx * inv;
            ysh[e][1] = 1.73205080756888f * dy * inv;
            ysh[e][2] = 1.73205080756888f * dz * inv;
        }
    }
    __syncthreads();

    const int rAll = rsh[lane];
    const int sAll = ssh[lane];
    const float y0A = ysh[lane][0], y1A = ysh[lane][1], y2A = ysh[lane][2];

    // ---- hoisted gathers: all 64 lines issued now; consumed after A1+A2 ---
    __half sregh[16];
    __half vr0h[16], vr1h[16], vr2h[16];
    #pragma unroll
    for (int i = 0; i < 16; ++i) {
        int snd = rl_i(sAll, w * 16 + i);
        sregh[i] = sUp2[snd * 64 + lane];
        vr0h[i]  = vUp2[snd * 192 +       lane];
        vr1h[i]  = vUp2[snd * 192 +  64 + lane];
        vr2h[i]  = vUp2[snd * 192 + 128 + lane];
    }

    // ---- A1 ----
    {
        float f[8];
        #pragma unroll
        for (int k = 0; k < 8; ++k) f[k] = fsh[lane][k];
        const float* __restrict__ w1b = W1 + w * 16;
        #pragma unroll
        for (int j = 0; j < 16; ++j) {
            float a = 0.f;
            #pragma unroll
            for (int k = 0; k < 8; ++k) a = fmaf(f[k], w1b[k * 64 + j], a);
            h1sh[lane][w * 16 + j] = silu(a);
        }
    }
    __syncthreads();

    // ---- A2 with split-bf16 epilogue ----
    {
        const float2* __restrict__ w2b = (const float2*)W2 + w * 8;
        float2 acc[8];
        #pragma unroll
        for (int j = 0; j < 8; ++j) acc[j] = make_float2(0.f, 0.f);
        for (int k = 0; k < 64; ++k) {
            float h = h1sh[lane][k];
            const float2* __restrict__ wk = w2b + k * 32;
            #pragma unroll
            for (int j = 0; j < 8; ++j) {
                float2 wv = wk[j];
                acc[j].x = fmaf(h, wv.x, acc[j].x);
                acc[j].y = fmaf(h, wv.y, acc[j].y);
            }
        }
        #pragma unroll
        for (int j = 0; j < 8; ++j) {
            uint2 p = split2(silu(acc[j].x), silu(acc[j].y));
            *(unsigned int*)&h2buf[0][lane][w * 16 + 2 * j] = p.x;
            *(unsigned int*)&h2buf[1][lane][w * 16 + 2 * j] = p.y;
        }
    }
    __syncthreads();   // last block-wide barrier; everything below is wave-local

    // ---- B: wave w owns edges [w*16, w*16+16) ----
    const int q = lane >> 4, nl = lane & 15;
    float* trw = (float*)(smem + 1280) + w * 2048;   // [16][128]

    const unsigned short* ar = &h2buf[0][w * 16 + nl][0];
    const unsigned short* al = &h2buf[1][w * 16 + nl][0];
    bf16x8 ah0 = *(const bf16x8*)(ar + q * 8);
    bf16x8 ah1 = *(const bf16x8*)(ar + 32 + q * 8);
    bf16x8 al0 = *(const bf16x8*)(al + q * 8);
    bf16x8 al1 = *(const bf16x8*)(al + 32 + q * 8);

    // ======== pass 0: channels 0..127 (mA, mB) ========
    #pragma unroll
    for (int nt = 0; nt < 8; ++nt) {
        int ng = nt * 16 + nl;
        const unsigned short* wh = w3h + ng * 64 + q * 8;
        const unsigned short* wl = w3l + ng * 64 + q * 8;
        bf16x8 bh0 = *(const bf16x8*)wh;
        bf16x8 bh1 = *(const bf16x8*)(wh + 32);
        bf16x8 bl0 = *(const bf16x8*)wl;
        bf16x8 bl1 = *(const bf16x8*)(wl + 32);
        f32x4 a = {0.f, 0.f, 0.f, 0.f};
        a = __builtin_amdgcn_mfma_f32_16x16x32_bf16(ah0, bh0, a, 0, 0, 0);
        a = __builtin_amdgcn_mfma_f32_16x16x32_bf16(ah1, bh1, a, 0, 0, 0);
        a = __builtin_amdgcn_mfma_f32_16x16x32_bf16(ah0, bl0, a, 0, 0, 0);
        a = __builtin_amdgcn_mfma_f32_16x16x32_bf16(ah1, bl1, a, 0, 0, 0);
        a = __builtin_amdgcn_mfma_f32_16x16x32_bf16(al0, bh0, a, 0, 0, 0);
        a = __builtin_amdgcn_mfma_f32_16x16x32_bf16(al1, bh1, a, 0, 0, 0);
        #pragma unroll
        for (int r = 0; r < 4; ++r) {
            int li = q * 4 + r;
            trw[li * 128 + ((ng + 4 * li) & 127)] = a[r];
        }
    }

    {
        float accS = 0.f, b0 = 0.f, b1 = 0.f, b2 = 0.f;
        int cur = rl_i(rAll, w * 16);
        #pragma unroll
        for (int i = 0; i < 16; ++i) {
            int e = w * 16 + i;
            int rcv = rl_i(rAll, e);
            if (rcv != cur) {
                unsafeAtomicAdd(&agS2[cur * 128 + lane], accS);
                unsafeAtomicAdd(&agV2[cur * 384 + 0 * 128 + lane], b0);
                unsafeAtomicAdd(&agV2[cur * 384 + 1 * 128 + lane], b1);
                unsafeAtomicAdd(&agV2[cur * 384 + 2 * 128 + lane], b2);
                accS = b0 = b1 = b2 = 0.f;
                cur = rcv;
            }
            float tv0 = trw[i * 128 + ((lane + 4 * i) & 127)];
            float tv1 = trw[i * 128 + ((64 + lane + 4 * i) & 127)];
            float se = __half2float(sregh[i]);
            accS += tv0 * se;
            float msg = tv1 * se;
            b0 += msg * rl_f(y0A, e);
            b1 += msg * rl_f(y1A, e);
            b2 += msg * rl_f(y2A, e);
        }
        unsafeAtomicAdd(&agS2[cur * 128 + lane], accS);
        unsafeAtomicAdd(&agV2[cur * 384 + 0 * 128 + lane], b0);
        unsafeAtomicAdd(&agV2[cur * 384 + 1 * 128 + lane], b1);
        unsafeAtomicAdd(&agV2[cur * 384 + 2 * 128 + lane], b2);
    }

    // ======== pass 1: channels 128..255 (mC, mD) ========
    #pragma unroll
    for (int nt = 0; nt < 8; ++nt) {
        int c  = nt * 16 + nl;       // local tr channel
        int ng = 128 + c;            // global weight channel
        const unsigned short* wh = w3h + ng * 64 + q * 8;
        const unsigned short* wl = w3l + ng * 64 + q * 8;
        bf16x8 bh0 = *(const bf16x8*)wh;
        bf16x8 bh1 = *(const bf16x8*)(wh + 32);
        bf16x8 bl0 = *(const bf16x8*)wl;
        bf16x8 bl1 = *(const bf16x8*)(wl + 32);
        f32x4 a = {0.f, 0.f, 0.f, 0.f};
        a = __builtin_amdgcn_mfma_f32_16x16x32_bf16(ah0, bh0, a, 0, 0, 0);
        a = __builtin_amdgcn_mfma_f32_16x16x32_bf16(ah1, bh1, a, 0, 0, 0);
        a = __builtin_amdgcn_mfma_f32_16x16x32_bf16(ah0, bl0, a, 0, 0, 0);
        a = __builtin_amdgcn_mfma_f32_16x16x32_bf16(ah1, bl1, a, 0, 0, 0);
        a = __builtin_amdgcn_mfma_f32_16x16x32_bf16(al0, bh0, a, 0, 0, 0);
        a = __builtin_amdgcn_mfma_f32_16x16x32_bf16(al1, bh1, a, 0, 0, 0);
        #pragma unroll
        for (int r = 0; r < 4; ++r) {
            int li = q * 4 + r;
            trw[li * 128 + ((c + 4 * li) & 127)] = a[r];
        }
    }

    {
        float accD = 0.f, c0 = 0.f, c1 = 0.f, c2 = 0.f;
        int cur = rl_i(rAll, w * 16);
        #pragma unroll
        for (int i = 0; i < 16; ++i) {
            int e = w * 16 + i;
            int rcv = rl_i(rAll, e);
            if (rcv != cur) {
                unsafeAtomicAdd(&agS2[cur * 128 + 64 + lane], accD);
                unsafeAtomicAdd(&agV2[cur * 384 + 0 * 128 + 64 + lane], c0);
                unsafeAtomicAdd(&agV2[cur * 384 + 1 * 128 + 64 + lane], c1);
                unsafeAtomicAdd(&agV2[cur * 384 + 2 * 128 + 64 + lane], c2);
                accD = c0 = c1 = c2 = 0.f;
                cur = rcv;
            }
            float tvC = trw[i * 128 + ((lane + 4 * i) & 127)];       // mC (1o x 0e)
            float tvD = trw[i * 128 + ((64 + lane + 4 * i) & 127)];  // mD (1o x 1o)
            float v0 = __half2float(vr0h[i]);
            float v1 = __half2float(vr1h[i]);
            float v2 = __half2float(vr2h[i]);
            c0 += tvC * v0;
            c1 += tvC * v1;
            c2 += tvC * v2;
            float dotvy = v0 * rl_f(y0A, e) + v1 * rl_f(y1A, e)
                        + v2 * rl_f(y2A, e);
            accD += tvD * dotvy * 0.577350269189626f;
        }
        unsafeAtomicAdd(&agS2[cur * 128 + 64 + lane], accD);
        unsafeAtomicAdd(&agV2[cur * 384 + 0 * 128 + 64 + lane], c0);
        unsafeAtomicAdd(&agV2[cur * 384 + 1 * 128 + 64 + lane], c1);
        unsafeAtomicAdd(&agV2[cur * 384 + 2 * 128 + 64 + lane], c2);
    }
}

// ---------------- node out ----------------
__global__ __launch_bounds__(256) void k_node_out(
    const float* __restrict__ L2s, const float* __restrict__ L2v,
    const float* __restrict__ agS2, const float* __restrict__ agV2,
    const float* __restrict__ skS2, const float* __restrict__ skV2,
    float* __restrict__ out)
{
    int lane = threadIdx.x & 63, wv = threadIdx.x >> 6;
    int n = blockIdx.x * 4 + wv;
    __shared__ __align__(16) float aS[4][128];
    __shared__ __align__(16) float aV[4][3][128];

    aS[wv][lane]      = agS2[n * 128 + lane];
    aS[wv][64 + lane] = agS2[n * 128 + 64 + lane];
    #pragma unroll
    for (int i = 0; i < 3; ++i) {
        aV[wv][i][lane]      = agV2[n * 384 + i * 128 + lane];
        aV[wv][i][64 + lane] = agV2[n * 384 + i * 128 + 64 + lane];
    }
    __syncthreads();

    float s2 = skS2[n * 64 + lane];
    #pragma unroll 8
    for (int u = 0; u < 128; ++u) s2 += aS[wv][u] * L2s[u * 64 + lane];
    float v2[3];
    #pragma unroll
    for (int i = 0; i < 3; ++i) v2[i] = skV2[n * 192 + i * 64 + lane];
    #pragma unroll 8
    for (int u = 0; u < 128; ++u) {
        float w = L2v[u * 64 + lane];
        v2[0] += aV[wv][0][u] * w;
        v2[1] += aV[wv][1][u] * w;
        v2[2] += aV[wv][2][u] * w;
    }
    out[(size_t)n * 256 + lane] = s2;
    #pragma unroll
    for (int i = 0; i < 3; ++i)
        out[(size_t)n * 256 + 64 + lane * 3 + i] = v2[i];
}

// ---------------- host launcher ----------------
extern "C" void kernel_launch(void* const* d_in, const int* in_sizes, int n_in,
                              void* d_out, int out_size, void* d_ws, size_t ws_size,
                              hipStream_t stream)
{
    (void)in_sizes; (void)n_in; (void)out_size; (void)ws_size;
    const float* positions  = (const float*)d_in[0];
    const float* node_attrs = (const float*)d_in[1];
    const int*   edge_index = (const int*)d_in[2];
    const float* shifts     = (const float*)d_in[3];
    const float* W_embed    = (const float*)d_in[4];
    const float* R1W1 = (const float*)d_in[5];
    const float* R1W2 = (const float*)d_in[6];
    const float* R1W3 = (const float*)d_in[7];
    const float* U1s  = (const float*)d_in[8];
    const float* L1s  = (const float*)d_in[9];
    const float* L1v  = (const float*)d_in[10];
    const float* K1s  = (const float*)d_in[11];
    const float* R2W1 = (const float*)d_in[12];
    const float* R2W2 = (const float*)d_in[13];
    const float* R2W3 = (const float*)d_in[14];
    const float* U2s  = (const float*)d_in[15];
    const float* U2v  = (const float*)d_in[16];
    const float* L2s  = (const float*)d_in[17];
    const float* L2v  = (const float*)d_in[18];
    const float* K2s  = (const float*)d_in[19];
    const float* K2v  = (const float*)d_in[20];

    float* wsf = (float*)d_ws;
    int*   wsi = (int*)(wsf + OFF_INT);
    int* hist   = wsi;
    int* cursor = wsi + 20000;
    int* sorted = wsi + 40000;
    unsigned short* wsh = (unsigned short*)(wsi + 360000);
    const unsigned short* w3a_hi = wsh;
    const unsigned short* w3a_lo = wsh + 8192;
    const unsigned short* w3b_hi = wsh + 16384;
    const unsigned short* w3b_lo = wsh + 32768;

    __half* sUp1h = (__half*)(wsf + OFF_SUP1);
    __half* sUp2h = (__half*)(wsf + OFF_SUP2);
    __half* vUp2h = (__half*)(wsf + OFF_VUP2);

    hipMemsetAsync(wsf + OFF_AGS1, 0, (size_t)4 * NC * sizeof(float), stream);
    hipMemsetAsync(hist, 0, 20000 * sizeof(int), stream);

    k_wsplit<<<96, 256, 0, stream>>>(R1W3, R2W3, wsh);
    k_hist<<<NEDGES / 256, 256, 0, stream>>>(edge_index, hist);
    k_scan<<<1, 1024, 0, stream>>>(hist, cursor);
    k_scatter<<<NEDGES / 256, 256, 0, stream>>>(edge_index, cursor, sorted);

    k_node_pre<<<NNODES / 4, 256, 0, stream>>>(node_attrs, W_embed, U1s, sUp1h);
    k_edge1<<<NEDGES / 64, 256, 0, stream>>>(positions, edge_index, shifts, sorted,
                                             R1W1, R1W2, w3a_hi, w3a_lo,
                                             sUp1h, wsf + OFF_AGS1, wsf + OFF_AGV1);
    k_node_mid<<<NNODES / 4, 256, 0, stream>>>(node_attrs, W_embed, K1s, L1s, L1v,
                                               U2s, U2v, K2s, K2v,
                                               wsf + OFF_AGS1, wsf + OFF_AGV1,
                                               sUp2h, vUp2h,
                                               wsf + OFF_SKS2, wsf + OFF_SKV2);
    hipMemsetAsync(wsf + OFF_AGS2, 0, (size_t)8 * NC * sizeof(float), stream);
    k_edge2<<<NEDGES / 64, 256, 0, stream>>>(positions, edge_index, shifts, sorted,
                                             R2W1, R2W2, w3b_hi, w3b_lo,
                                             sUp2h, vUp2h,
                                             wsf + OFF_AGS2, wsf + OFF_AGV2);
    k_node_out<<<NNODES / 4, 256, 0, stream>>>(L2s, L2v, wsf + OFF_AGS2, wsf + OFF_AGV2,
                                               wsf + OFF_SKS2, wsf + OFF_SKV2,
                                               (float*)d_out);
}